// Round 2
// baseline (705.557 us; speedup 1.0000x reference)
//
#include <hip/hip_runtime.h>

#define DIM 128
#define NUM_GRAPHS 512
#define NPB 512            // nodes per block (8 groups x 64)
#define NPT 64             // nodes per thread-group run

typedef float f4 __attribute__((ext_vector_type(4)));
typedef int   i4 __attribute__((ext_vector_type(4)));

// Route a partial sum to the block's first-graph slot (acc0) or last-graph
// slot (acc1). Graphs strictly inside the block (>=3 graphs per block --
// never with ~1953-node segments) are skipped and recomputed by stage 2.
__device__ __forceinline__ void route(f4 s, float n, int gg, int bg0, int bg1,
                                      f4& acc0, f4& acc1, float& c0, float& c1) {
    if (gg == bg0)      { acc0 += s; c0 += n; }
    else if (gg == bg1) { acc1 += s; c1 += n; }
}

// ---------------------------------------------------------------------------
// Stage 1 (fused): blocks [0,nb) do the atomic-free segment partial-sum;
// blocks [nb, nb+ncopy) do the int32->float32 pass-through copies.
// Per seg-block: 8 groups x 64 nodes, each thread owns one 16B dim-chunk.
// LDS tree-reduce across the 8 groups -> write (partial0, partial1, gids,
// counts) per block. Workspace is overwritten, never read-modify-written:
// no memset, no atomics, fully deterministic.
// ---------------------------------------------------------------------------
__global__ __launch_bounds__(256) void stage1_kernel(
    const float* __restrict__ x, const int* __restrict__ batch,
    int2* __restrict__ gids, float2* __restrict__ cnts,
    float* __restrict__ p0, float* __restrict__ p1,
    int n_nodes, int nb,
    const i4* __restrict__ e, f4* __restrict__ eo, long long ne4,
    const i4* __restrict__ bt, f4* __restrict__ bo, long long nb4)
{
    __shared__ float s0[8][DIM];
    __shared__ float s1[8][DIM];
    __shared__ float sc[8][2];

    if ((int)blockIdx.x >= nb) {
        // ---- pass-through copy blocks (independent work, overlaps seg-sum)
        long long i = (long long)(blockIdx.x - nb) * 256 + threadIdx.x;
        if (i < ne4) {
            i4 v = __builtin_nontemporal_load(e + i);
            f4 o = { (float)v.x, (float)v.y, (float)v.z, (float)v.w };
            __builtin_nontemporal_store(o, eo + i);
        } else {
            long long j = i - ne4;
            if (j < nb4) {
                i4 v = __builtin_nontemporal_load(bt + j);
                f4 o = { (float)v.x, (float)v.y, (float)v.z, (float)v.w };
                __builtin_nontemporal_store(o, bo + j);
            }
        }
        return;
    }

    const int chunk = threadIdx.x & 31;
    const int group = threadIdx.x >> 5;
    const int blk   = blockIdx.x;
    const long long base  = (long long)blk * NPB;
    const long long node0 = base + (long long)group * NPT;
    long long blast = base + NPB; if (blast > n_nodes) blast = n_nodes;
    const int bg0 = batch[base];
    const int bg1 = batch[blast - 1];

    f4 acc0 = (f4)0.f, acc1 = (f4)0.f;
    float c0 = 0.f, c1 = 0.f;

    if (node0 < n_nodes) {
        int cnt = NPT;
        if (node0 + NPT > n_nodes) cnt = (int)(n_nodes - node0);
        const f4* __restrict__ p = (const f4*)x + node0 * 32 + chunk;

        int g0 = batch[node0];
        int g1 = batch[node0 + cnt - 1];

        if (g0 == g1) {
            // fast path: whole 64-node run in one segment -- pipelined stream
            f4 a = (f4)0.f, b = (f4)0.f;
            int i = 0;
            #pragma unroll 4
            for (; i + 1 < cnt; i += 2) {
                f4 v0 = __builtin_nontemporal_load(p + (long long)i * 32);
                f4 v1 = __builtin_nontemporal_load(p + (long long)(i + 1) * 32);
                a += v0; b += v1;
            }
            if (i < cnt) a += __builtin_nontemporal_load(p + (long long)i * 32);
            route(a + b, (float)cnt, g0, bg0, bg1, acc0, acc1, c0, c1);
        } else if (g1 - g0 == 1) {
            // exactly one boundary: binary search the split (batch sorted)
            int lo = 1, hi = cnt - 1;
            while (lo < hi) {
                int mid = (lo + hi) >> 1;
                if (batch[node0 + mid] == g0) lo = mid + 1; else hi = mid;
            }
            f4 a = (f4)0.f;
            for (int i = 0; i < lo; ++i)
                a += __builtin_nontemporal_load(p + (long long)i * 32);
            route(a, (float)lo, g0, bg0, bg1, acc0, acc1, c0, c1);
            a = (f4)0.f;
            for (int i = lo; i < cnt; ++i)
                a += __builtin_nontemporal_load(p + (long long)i * 32);
            route(a, (float)(cnt - lo), g1, bg0, bg1, acc0, acc1, c0, c1);
        } else {
            // generic fallback (never hit with ~1953-node segments)
            for (int i = 0; i < cnt; ++i) {
                int g = batch[node0 + i];
                f4 v = __builtin_nontemporal_load(p + (long long)i * 32);
                route(v, 1.f, g, bg0, bg1, acc0, acc1, c0, c1);
            }
        }
    }

    *(f4*)&s0[group][chunk * 4] = acc0;
    *(f4*)&s1[group][chunk * 4] = acc1;
    if (chunk == 0) { sc[group][0] = c0; sc[group][1] = c1; }
    __syncthreads();

    #pragma unroll
    for (int st = 4; st >= 1; st >>= 1) {
        if (group < st) {
            *(f4*)&s0[group][chunk * 4] += *(const f4*)&s0[group + st][chunk * 4];
            *(f4*)&s1[group][chunk * 4] += *(const f4*)&s1[group + st][chunk * 4];
            if (chunk < 2) sc[group][chunk] += sc[group + st][chunk];
        }
        __syncthreads();
    }

    if (group == 0) {
        *(f4*)(p0 + (size_t)blk * DIM + chunk * 4) = *(const f4*)&s0[0][chunk * 4];
    } else if (group == 1) {
        *(f4*)(p1 + (size_t)blk * DIM + chunk * 4) = *(const f4*)&s1[0][chunk * 4];
    } else if (group == 2 && chunk == 0) {
        gids[blk] = make_int2(bg0, bg1);
        cnts[blk] = make_float2(sc[0][0], sc[0][1]);
    }
}

// ---------------------------------------------------------------------------
// Stage 2: per graph, gather the ~4-5 block partials (binary search over the
// nondecreasing per-block gid bounds), divide by count, then the folded MLP:
// pooled = (sum/cnt) @ W1 @ W2 + (b1 @ W2 + b2)  (mean commutes, no acts).
// Middle-graph recompute path kept for full generality (never hit here).
// ---------------------------------------------------------------------------
__global__ __launch_bounds__(DIM) void stage2_kernel(
    const int2* __restrict__ gids, const float2* __restrict__ cnts,
    const float* __restrict__ p0, const float* __restrict__ p1,
    const float* __restrict__ x, const int* __restrict__ batch,
    int n_nodes, int nb,
    const float* __restrict__ W1, const float* __restrict__ b1,
    const float* __restrict__ W2, const float* __restrict__ b2,
    float* __restrict__ out)
{
    __shared__ float xrow[DIM];
    __shared__ float yrow[DIM];
    const int g = blockIdx.x;
    const int t = threadIdx.x;

    int lo, hi;
    { int a = 0, b = nb - 1;                       // first block with gid1 >= g
      while (a < b) { int m = (a + b) >> 1; if (gids[m].y < g) a = m + 1; else b = m; }
      lo = a; }
    { int a = 0, b = nb - 1;                       // last block with gid0 <= g
      while (a < b) { int m = (a + b + 1) >> 1; if (gids[m].x > g) b = m - 1; else a = m; }
      hi = a; }

    float sum = 0.f, cnt = 0.f;
    for (int b = lo; b <= hi; ++b) {
        const int2 id = gids[b];
        const float2 c = cnts[b];
        if (id.x == g) { sum += p0[(size_t)b * DIM + t]; cnt += c.x; }
        if (id.y == g && id.y != id.x) { sum += p1[(size_t)b * DIM + t]; cnt += c.y; }
        if (id.x < g && g < id.y) {
            // graph strictly inside block b: recompute directly (never hit)
            long long s = (long long)b * NPB;
            long long e2 = s + NPB; if (e2 > n_nodes) e2 = n_nodes;
            long long a1 = s, bb = e2;
            while (a1 < bb) { long long m = (a1 + bb) >> 1; if (batch[m] <  g) a1 = m + 1; else bb = m; }
            long long a2 = a1, bb2 = e2;
            while (a2 < bb2) { long long m = (a2 + bb2) >> 1; if (batch[m] <= g) a2 = m + 1; else bb2 = m; }
            for (long long nidx = a1; nidx < a2; ++nidx) sum += x[nidx * DIM + t];
            cnt += (float)(a2 - a1);
        }
    }

    xrow[t] = sum / cnt;
    __syncthreads();
    float acc = b1[t];
    #pragma unroll 8
    for (int k = 0; k < DIM; ++k) acc += xrow[k] * W1[k * DIM + t];
    yrow[t] = acc;
    __syncthreads();
    float acc2 = b2[t];
    #pragma unroll 8
    for (int k = 0; k < DIM; ++k) acc2 += yrow[k] * W2[k * DIM + t];
    out[(size_t)g * DIM + t] = acc2;
}

extern "C" void kernel_launch(void* const* d_in, const int* in_sizes, int n_in,
                              void* d_out, int out_size, void* d_ws, size_t ws_size,
                              hipStream_t stream) {
    const float* x     = (const float*)d_in[0];
    const int*   edge  = (const int*)d_in[1];
    const int*   batch = (const int*)d_in[2];
    const float* W1    = (const float*)d_in[3];
    const float* b1    = (const float*)d_in[4];
    const float* W2    = (const float*)d_in[5];
    const float* b2    = (const float*)d_in[6];
    float* out = (float*)d_out;

    long long edge_n  = in_sizes[1];   // 4,000,000 int32
    long long n_nodes = in_sizes[2];   // 1,000,000
    int nb = (int)((n_nodes + NPB - 1) / NPB);

    // workspace carve (every byte stage 2 reads is written by stage 1 --
    // poison-safe without any memset)
    char* w = (char*)d_ws;
    int2*   gids = (int2*)w;   w += ((size_t)nb * sizeof(int2)        + 255) & ~(size_t)255;
    float2* cnts = (float2*)w; w += ((size_t)nb * sizeof(float2)      + 255) & ~(size_t)255;
    float*  p0   = (float*)w;  w += ((size_t)nb * DIM * sizeof(float) + 255) & ~(size_t)255;
    float*  p1   = (float*)w;

    float* edge_out  = out + (size_t)NUM_GRAPHS * DIM;
    float* batch_out = edge_out + edge_n;
    long long ne4 = edge_n >> 2, nb4 = n_nodes >> 2;
    int ncopy = (int)((ne4 + nb4 + 255) / 256);

    stage1_kernel<<<nb + ncopy, 256, 0, stream>>>(
        x, batch, gids, cnts, p0, p1, (int)n_nodes, nb,
        (const i4*)edge, (f4*)edge_out, ne4,
        (const i4*)batch, (f4*)batch_out, nb4);

    stage2_kernel<<<NUM_GRAPHS, DIM, 0, stream>>>(
        gids, cnts, p0, p1, x, batch, (int)n_nodes, nb,
        W1, b1, W2, b2, out);
}